// Round 2
// baseline (1179.734 us; speedup 1.0000x reference)
//
#include <hip/hip_runtime.h>
#include <hip/hip_bf16.h>

// SimpleRNN fused persistent kernel, round 6.
// T=512, B=1024, IN=128, H=256, OUT=4, K=384. 64 WGs x 16 batch rows, 8 waves.
// Change vs r5: step-time audit shows ~65% of the 2500-cyc step is LDS-pipe
// occupancy (96 b128 reads ~1150cyc + 448 conflict cyc + writes), burst-issued
// by all 8 barrier-locked waves. A third of that traffic is x -- which needs
// no cross-wave exchange at all:
//  - x B-frags now built from per-lane GLOBAL loads (contiguous 32B/lane,
//    8x dwordx4, issued a full step ahead -> ~2000 cyc latency cover, lands
//    on the idle vmem pipe; 8KB x-tile is L1-resident for all 8 waves).
//  - x LDS ring, x staging writes, x LDS reads all deleted. LDS 32KB -> 16KB.
//  - everything else (2 h-tiles + replicated logits per wave, VGPR gate
//    table, collapsed XOR-swizzle offsets, pre-barrier x-MFMAs, 1 lgkm-only
//    barrier/step) unchanged from r5.

#define TT    512
#define BBAT  1024
#define INDIM 128
#define HDIM  256
#define KDIM  384
#define NB    16
#define HREG  8192    // one h buffer: 16 rows x 512 B (ping-pong at 0 / HREG)

typedef __attribute__((ext_vector_type(8))) __bf16 bf16x8;
typedef __attribute__((ext_vector_type(4))) float  fx4;
typedef __attribute__((ext_vector_type(4))) unsigned int ui4;

__device__ __forceinline__ __bf16 f2bf(float f) {
  unsigned u = __builtin_bit_cast(unsigned, f);
  unsigned short r = (unsigned short)((u + 0x7FFFu + ((u >> 16) & 1u)) >> 16);
  return __builtin_bit_cast(__bf16, r);
}

// LDS-only barrier: waits DS ops, does NOT drain vmcnt (in-flight global
// loads/stores are wave-private; all cross-wave traffic goes through LDS).
__device__ __forceinline__ void ldsbar() {
  asm volatile("s_waitcnt lgkmcnt(0)\n\ts_barrier" ::: "memory");
}

__global__ __launch_bounds__(512, 2) void rnn_fused(
    const float* __restrict__ inp,     // [T,B,IN]
    const float* __restrict__ hidden,  // [B,H]
    const float* __restrict__ Wih,     // [H, K]
    const float* __restrict__ bih,     // [H]
    const float* __restrict__ Wio,     // [4, K]
    const float* __restrict__ bio,     // [4]
    const float* __restrict__ act,     // [4, H]
    float* __restrict__ out)           // [T*B*4] ++ [B*H]
{
  __shared__ __align__(16) char lds[2 * HREG];

  const int tid  = threadIdx.x;
  const int wave = tid >> 6;    // [0,8): h-tiles {2w, 2w+1}
  const int lane = tid & 63;
  const int l15  = lane & 15;   // batch row (B-frag col / D col)
  const int qq   = lane >> 4;
  const int b0   = blockIdx.x * NB;
  const int swz  = l15 & 7;

  float* outs = out;
  float* hs0  = out + (long)TT * BBAT * 4;

  const float C2 = 2.8853900817779268f;  // 2*log2(e)

  // ---- x pipeline: per-lane direct global loads (contiguous 32 B/lane) ----
  // B-frag for col l15 needs x[t][b0+l15][kc*32 + qq*8 + i], i=0..7, kc=0..3.
  const float* xlp = inp + (long)(b0 + l15) * INDIM + qq * 8;
  fx4 xld[4][2];                 // x[t+1] f32 in flight (issued 1 step ahead)
  auto loadxg = [&](int t) {
    const float* p = xlp + (long)t * (BBAT * INDIM);
#pragma unroll
    for (int kc = 0; kc < 4; ++kc) {
      xld[kc][0] = *(const fx4*)(p + kc * 32);
      xld[kc][1] = *(const fx4*)(p + kc * 32 + 4);
    }
  };
  auto cvtx = [&](bf16x8* xb) {
#pragma unroll
    for (int kc = 0; kc < 4; ++kc) {
      union { bf16x8 b; __hip_bfloat162 h2[4]; } pk;
      pk.h2[0] = __float22bfloat162_rn(make_float2(xld[kc][0][0], xld[kc][0][1]));
      pk.h2[1] = __float22bfloat162_rn(make_float2(xld[kc][0][2], xld[kc][0][3]));
      pk.h2[2] = __float22bfloat162_rn(make_float2(xld[kc][1][0], xld[kc][1][1]));
      pk.h2[3] = __float22bfloat162_rn(make_float2(xld[kc][1][2], xld[kc][1][3]));
      xb[kc] = pk.b;
    }
  };

  loadxg(0);   // x[0] in flight across all of init (huge cover)

  // ---- one-time LDS init: h0 into buffer 0 (swizzled) ----
  {
    const int row = tid >> 5, cg = tid & 31;   // 8 floats of h per thread
    const float* hp = hidden + (long)(b0 + row) * HDIM + cg * 8;
    union { ui4 v; __hip_bfloat162 h2[4]; } pk;
    pk.h2[0] = __float22bfloat162_rn(make_float2(hp[0], hp[1]));
    pk.h2[1] = __float22bfloat162_rn(make_float2(hp[2], hp[3]));
    pk.h2[2] = __float22bfloat162_rn(make_float2(hp[4], hp[5]));
    pk.h2[3] = __float22bfloat162_rn(make_float2(hp[6], hp[7]));
    *(ui4*)(&lds[0] + row * 512 + ((cg ^ (row & 7)) << 4)) = pk.v;
  }

  // ---- loop-invariant weight A-frags: 2 h-tiles + replicated logits tile ----
  bf16x8 Wfr[3][12];
#pragma unroll
  for (int j = 0; j < 3; ++j) {
    const float* wbase = (j < 2) ? (Wih + (long)((wave * 2 + j) * 16 + l15) * KDIM)
                                 : (Wio + (long)(l15 & 3) * KDIM);
#pragma unroll
    for (int kc = 0; kc < 12; ++kc) {
      const float* wp = wbase + kc * 32 + qq * 8;
      bf16x8 f;
#pragma unroll
      for (int i = 0; i < 8; ++i) f[i] = f2bf(wp[i]);
      Wfr[j][kc] = f;
    }
  }

  // gates packed bf16: abf[qi] elems (j*4+r) = act[qi][(wave*2+j)*16+qq*4+r]
  ui4 abf[4];
#pragma unroll
  for (int qi = 0; qi < 4; ++qi) {
    const fx4 a0 = *(const fx4*)&act[qi * HDIM + (wave * 2 + 0) * 16 + qq * 4];
    const fx4 a1 = *(const fx4*)&act[qi * HDIM + (wave * 2 + 1) * 16 + qq * 4];
    union { ui4 v; __hip_bfloat162 h2[4]; } pk;
    pk.h2[0] = __float22bfloat162_rn(make_float2(a0[0], a0[1]));
    pk.h2[1] = __float22bfloat162_rn(make_float2(a0[2], a0[3]));
    pk.h2[2] = __float22bfloat162_rn(make_float2(a1[0], a1[1]));
    pk.h2[3] = __float22bfloat162_rn(make_float2(a1[2], a1[3]));
    abf[qi] = pk.v;
  }

  fx4 cbz[2];
#pragma unroll
  for (int j = 0; j < 2; ++j)
    cbz[j] = (*(const fx4*)&bih[(wave * 2 + j) * 16 + qq * 4]) * C2;
  const fx4 bo = *(const fx4*)&bio[0];

  // ---- collapsed swizzled LDS offsets (h only) ----
  // chunk(kc) = (kc*4+qq)^swz  ->  off = B0 + ((kc&1)^b)<<6 + (kc>>1)<<7
  const int B0  = (qq ^ (swz & 3)) << 4;
  const int b64 = (swz & 4) << 4;
  const int hE = l15 * 512 + B0 + b64;        // even kc, + (kc>>1)*128 imm
  const int hO = l15 * 512 + B0 + 64 - b64;   // odd  kc
  int woffH[2];
#pragma unroll
  for (int j = 0; j < 2; ++j)
    woffH[j] = l15 * 512 +
               (((wave * 4 + j * 2 + (qq >> 1)) ^ swz) << 4) + (qq & 1) * 8;

  __syncthreads();

  // accumulators persist across steps: at loop top they hold x[t]-part
  fx4 acc[2], accL;
  {
    bf16x8 xb[4];
    cvtx(xb);                    // x[0] (loaded pre-init)
    const fx4 z4 = {0.f, 0.f, 0.f, 0.f};
    accL = z4; acc[0] = z4; acc[1] = z4;
#pragma unroll
    for (int kc = 0; kc < 4; ++kc) {
      accL   = __builtin_amdgcn_mfma_f32_16x16x32_bf16(Wfr[2][kc], xb[kc], accL, 0, 0, 0);
      acc[0] = __builtin_amdgcn_mfma_f32_16x16x32_bf16(Wfr[0][kc], xb[kc], acc[0], 0, 0, 0);
      acc[1] = __builtin_amdgcn_mfma_f32_16x16x32_bf16(Wfr[1][kc], xb[kc], acc[1], 0, 0, 0);
    }
  }
  loadxg(1);                     // x[1] in flight across step 0

  // ---- one RNN step (ph = t&1, compile-time at every callsite) ----
  auto stepf = [&](int t, const int ph) {
    const char* hR = &lds[ph * HREG];          // h[t]
    char*       hW = &lds[(ph ^ 1) * HREG];    // h[t+1]

    // 1) h B-frag reads (head of the post-barrier chain)
    bf16x8 hbA[4], hbB[4];
    hbA[0] = *(const bf16x8*)(hR + hE);
    hbA[1] = *(const bf16x8*)(hR + hO);
    hbA[2] = *(const bf16x8*)(hR + hE + 128);
    hbA[3] = *(const bf16x8*)(hR + hO + 128);
    hbB[0] = *(const bf16x8*)(hR + hE + 256);
    hbB[1] = *(const bf16x8*)(hR + hO + 256);
    hbB[2] = *(const bf16x8*)(hR + hE + 384);
    hbB[3] = *(const bf16x8*)(hR + hO + 384);

    // 2) 24 h-MFMAs (logits acc first so argmax can start early)
#pragma unroll
    for (int kc = 0; kc < 4; ++kc) {
      accL   = __builtin_amdgcn_mfma_f32_16x16x32_bf16(Wfr[2][kc + 4], hbA[kc], accL, 0, 0, 0);
      acc[0] = __builtin_amdgcn_mfma_f32_16x16x32_bf16(Wfr[0][kc + 4], hbA[kc], acc[0], 0, 0, 0);
      acc[1] = __builtin_amdgcn_mfma_f32_16x16x32_bf16(Wfr[1][kc + 4], hbA[kc], acc[1], 0, 0, 0);
    }
#pragma unroll
    for (int kc = 0; kc < 4; ++kc) {
      accL   = __builtin_amdgcn_mfma_f32_16x16x32_bf16(Wfr[2][kc + 8], hbB[kc], accL, 0, 0, 0);
      acc[0] = __builtin_amdgcn_mfma_f32_16x16x32_bf16(Wfr[0][kc + 8], hbB[kc], acc[0], 0, 0, 0);
      acc[1] = __builtin_amdgcn_mfma_f32_16x16x32_bf16(Wfr[1][kc + 8], hbB[kc], acc[1], 0, 0, 0);
    }

    // 3) logits: every lane has all 4 logits of its batch row
    const fx4 lg = accL + bo;
    int qi = 0; float bv = lg[0];
    if (lg[1] > bv) { bv = lg[1]; qi = 1; }
    if (lg[2] > bv) { bv = lg[2]; qi = 2; }
    if (lg[3] > bv) { bv = lg[3]; qi = 3; }
    if (wave == 0 && qq == 0)
      *(fx4*)&outs[((long)t * BBAT + b0 + l15) * 4] = lg;   // 256B coalesced

    // 4) gate select from packed-bf16 table (cndmask, no LDS)
    const bool s0 = (qi & 1) != 0, s1 = (qi & 2) != 0;
    const ui4 ga = s0 ? abf[1] : abf[0];
    const ui4 gb = s0 ? abf[3] : abf[2];
    const ui4 g  = s1 ? gb : ga;

    // 5) epilogue: th = tanh(acc+bias) = 1 - 2/(exp2(C2*acc + C2*b) + 1)
#pragma unroll
    for (int j = 0; j < 2; ++j) {
      const fx4 z = acc[j] * C2 + cbz[j];
      fx4 th;
#pragma unroll
      for (int r = 0; r < 4; ++r) {
        const float e  = __builtin_amdgcn_exp2f(z[r]);
        const float rc = __builtin_amdgcn_rcpf(e + 1.0f);
        th[r] = fmaf(-2.0f, rc, 1.0f);
      }
      if (ph == 0 && t == 0)
        *(fx4*)&hs0[(long)(b0 + l15) * HDIM + (wave * 2 + j) * 16 + qq * 4] = th;
      // h_next = th + th*a  (a = act[qi][...] in bf16; |err| ~4e-5 << bf16-h ulp)
      const unsigned ug0 = g[j * 2 + 0], ug1 = g[j * 2 + 1];
      const float a0 = __builtin_bit_cast(float, ug0 << 16);
      const float a1 = __builtin_bit_cast(float, ug0 & 0xFFFF0000u);
      const float a2 = __builtin_bit_cast(float, ug1 << 16);
      const float a3 = __builtin_bit_cast(float, ug1 & 0xFFFF0000u);
      fx4 hg;
      hg[0] = fmaf(th[0], a0, th[0]);
      hg[1] = fmaf(th[1], a1, th[1]);
      hg[2] = fmaf(th[2], a2, th[2]);
      hg[3] = fmaf(th[3], a3, th[3]);
      union { unsigned long long u; __hip_bfloat162 h2[2]; } pk;
      pk.h2[0] = __float22bfloat162_rn(make_float2(hg[0], hg[1]));
      pk.h2[1] = __float22bfloat162_rn(make_float2(hg[2], hg[3]));
      *(unsigned long long*)(hW + woffH[j]) = pk.u;
    }

    // 6) x-part MFMAs for step t+1 from registers (pre-barrier: fills skew
    //    slack, shortens next step's post-barrier chain to h-only), then
    //    issue global loads for x[t+2] (a full step of latency cover)
    if (t + 1 < TT) {
      bf16x8 xb[4];
      cvtx(xb);                  // waits vmcnt on loads issued one step ago
      const fx4 z4 = {0.f, 0.f, 0.f, 0.f};
      accL = z4; acc[0] = z4; acc[1] = z4;
#pragma unroll
      for (int kc = 0; kc < 4; ++kc) {
        accL   = __builtin_amdgcn_mfma_f32_16x16x32_bf16(Wfr[2][kc], xb[kc], accL, 0, 0, 0);
        acc[0] = __builtin_amdgcn_mfma_f32_16x16x32_bf16(Wfr[0][kc], xb[kc], acc[0], 0, 0, 0);
        acc[1] = __builtin_amdgcn_mfma_f32_16x16x32_bf16(Wfr[1][kc], xb[kc], acc[1], 0, 0, 0);
      }
      if (t + 2 < TT) loadxg(t + 2);
    }

    ldsbar();   // single barrier per step
  };

#pragma unroll 1
  for (int t = 0; t < TT; t += 2) {
    stepf(t,     0);
    stepf(t + 1, 1);
  }
}

extern "C" void kernel_launch(void* const* d_in, const int* in_sizes, int n_in,
                              void* d_out, int out_size, void* d_ws, size_t ws_size,
                              hipStream_t stream) {
  const float* inp    = (const float*)d_in[0];
  const float* hidden = (const float*)d_in[1];
  const float* Wih    = (const float*)d_in[2];
  const float* bih    = (const float*)d_in[3];
  const float* Wio    = (const float*)d_in[4];
  const float* bio    = (const float*)d_in[5];
  const float* act    = (const float*)d_in[6];
  float* out = (float*)d_out;
  rnn_fused<<<dim3(BBAT / NB), dim3(512), 0, stream>>>(
      inp, hidden, Wih, bih, Wio, bio, act, out);
}

// Round 4
// 833.480 us; speedup vs baseline: 1.4154x; 1.4154x over previous
//
#include <hip/hip_runtime.h>
#include <hip/hip_bf16.h>

// SimpleRNN fused persistent kernel, round 8.
// T=512, B=1024, IN=128, H=256, OUT=4, K=384. 64 WGs x 16 batch rows, 8 waves.
// r7 post-mortem: bundled 5 structural deltas, failed correctness (0.73),
// fault not isolatable by inspection. r8 rebuilds from r5 (verified 532us)
// with ONLY association-preserving, sync-margin-preserving deltas:
//  - x-MFMAs moved from prev-step tail to step top. Chain order per
//    accumulator unchanged (x kc0-3 then h kc0-7) -> bitwise-identical
//    trajectory to r5. They now execute under the h ds_read return latency
//    instead of delaying barrier arrival; the step tail is 12 MFMAs shorter.
//  - s_setprio(1)/(0) around the MFMA cluster (T5; natural phase split
//    between the 2 waves/SIMD: one issuing ds_reads, one in MFMAs).
//  - 4-slot x ring, phase-3 xb reads, swizzled offsets, bf16 gate table,
//    epilogue, init: r5-verbatim.

#define TT    512
#define BBAT  1024
#define INDIM 128
#define HDIM  256
#define KDIM  384
#define NB    16
#define HREG  8192    // one h buffer: 16 rows x 512 B (ping-pong at 0 / HREG)
#define XOFF  16384   // x ring: 4 slots x 4096 B (16 rows x 256 B)
#define XSLOT 4096

typedef __attribute__((ext_vector_type(8))) __bf16 bf16x8;
typedef __attribute__((ext_vector_type(4))) float  fx4;
typedef __attribute__((ext_vector_type(4))) unsigned int ui4;

__device__ __forceinline__ __bf16 f2bf(float f) {
  unsigned u = __builtin_bit_cast(unsigned, f);
  unsigned short r = (unsigned short)((u + 0x7FFFu + ((u >> 16) & 1u)) >> 16);
  return __builtin_bit_cast(__bf16, r);
}

// LDS-only barrier: waits DS ops, does NOT drain vmcnt (in-flight global
// loads/stores are wave-private; all cross-wave traffic goes through LDS).
__device__ __forceinline__ void ldsbar() {
  asm volatile("s_waitcnt lgkmcnt(0)\n\ts_barrier" ::: "memory");
}

__global__ __launch_bounds__(512, 2) void rnn_fused(
    const float* __restrict__ inp,     // [T,B,IN]
    const float* __restrict__ hidden,  // [B,H]
    const float* __restrict__ Wih,     // [H, K]
    const float* __restrict__ bih,     // [H]
    const float* __restrict__ Wio,     // [4, K]
    const float* __restrict__ bio,     // [4]
    const float* __restrict__ act,     // [4, H]
    float* __restrict__ out)           // [T*B*4] ++ [B*H]
{
  __shared__ __align__(16) char lds[2 * HREG + 4 * XSLOT];

  const int tid  = threadIdx.x;
  const int wave = tid >> 6;    // [0,8): h-tiles {2w, 2w+1}
  const int lane = tid & 63;
  const int l15  = lane & 15;   // batch row (B-frag col / D col)
  const int qq   = lane >> 4;
  const int b0   = blockIdx.x * NB;
  const int swz  = l15 & 7;

  float* outs = out;
  float* hs0  = out + (long)TT * BBAT * 4;

  const float C2 = 2.8853900817779268f;  // 2*log2(e)

  // ---- x pipeline: 512-thread cooperative staging, 2-reg ring ----
  const int xrow = tid >> 5, xcg = tid & 31;   // row[0,16) x 4-float chunk[0,32)
  fx4 xs[2];                                    // x[m] lives in xs[m&1]
  auto loadx = [&](int t, int s) {
    if (t < TT)
      xs[s] = *(const fx4*)(inp + ((long)t * BBAT + b0 + xrow) * INDIM + xcg * 4);
  };
  const int xwoff = xrow * 256 + (((xcg >> 1) ^ (xrow & 7)) << 4) + (xcg & 1) * 8;
  auto writex = [&](int s, char* dst) {
    union { unsigned long long u; __hip_bfloat162 h2[2]; } pk;
    pk.h2[0] = __float22bfloat162_rn(make_float2(xs[s][0], xs[s][1]));
    pk.h2[1] = __float22bfloat162_rn(make_float2(xs[s][2], xs[s][3]));
    *(unsigned long long*)(dst + xwoff) = pk.u;
  };

  // ---- one-time init: h0 -> hbuf0, x0/x1 -> ring slots 0/1, x2 -> xs[0] ----
  loadx(0, 0);
  {
    const int row = tid >> 5, cg = tid & 31;   // 8 floats of h per thread
    const float* hp = hidden + (long)(b0 + row) * HDIM + cg * 8;
    union { ui4 v; __hip_bfloat162 h2[4]; } pk;
    pk.h2[0] = __float22bfloat162_rn(make_float2(hp[0], hp[1]));
    pk.h2[1] = __float22bfloat162_rn(make_float2(hp[2], hp[3]));
    pk.h2[2] = __float22bfloat162_rn(make_float2(hp[4], hp[5]));
    pk.h2[3] = __float22bfloat162_rn(make_float2(hp[6], hp[7]));
    *(ui4*)(&lds[0] + row * 512 + ((cg ^ (row & 7)) << 4)) = pk.v;
  }
  writex(0, &lds[XOFF + 0 * XSLOT]);   // x[0] -> slot 0
  loadx(1, 1);
  writex(1, &lds[XOFF + 1 * XSLOT]);   // x[1] -> slot 1
  loadx(2, 0);                          // x[2] staged at step-0 tail

  // ---- loop-invariant weight A-frags: 2 h-tiles + replicated logits tile ----
  bf16x8 Wfr[3][12];
#pragma unroll
  for (int j = 0; j < 3; ++j) {
    const float* wbase = (j < 2) ? (Wih + (long)((wave * 2 + j) * 16 + l15) * KDIM)
                                 : (Wio + (long)(l15 & 3) * KDIM);
#pragma unroll
    for (int kc = 0; kc < 12; ++kc) {
      const float* wp = wbase + kc * 32 + qq * 8;
      bf16x8 f;
#pragma unroll
      for (int i = 0; i < 8; ++i) f[i] = f2bf(wp[i]);
      Wfr[j][kc] = f;
    }
  }

  // gates packed bf16: abf[qi] elems (j*4+r) = act[qi][(wave*2+j)*16+qq*4+r]
  ui4 abf[4];
#pragma unroll
  for (int qi = 0; qi < 4; ++qi) {
    const fx4 a0 = *(const fx4*)&act[qi * HDIM + (wave * 2 + 0) * 16 + qq * 4];
    const fx4 a1 = *(const fx4*)&act[qi * HDIM + (wave * 2 + 1) * 16 + qq * 4];
    union { ui4 v; __hip_bfloat162 h2[4]; } pk;
    pk.h2[0] = __float22bfloat162_rn(make_float2(a0[0], a0[1]));
    pk.h2[1] = __float22bfloat162_rn(make_float2(a0[2], a0[3]));
    pk.h2[2] = __float22bfloat162_rn(make_float2(a1[0], a1[1]));
    pk.h2[3] = __float22bfloat162_rn(make_float2(a1[2], a1[3]));
    abf[qi] = pk.v;
  }

  fx4 cbz[2];
#pragma unroll
  for (int j = 0; j < 2; ++j)
    cbz[j] = (*(const fx4*)&bih[(wave * 2 + j) * 16 + qq * 4]) * C2;
  const fx4 bo = *(const fx4*)&bio[0];

  // ---- collapsed swizzled LDS offsets ----
  // chunk(kc) = (kc*4+qq)^swz  ->  off = B0 + ((kc&1)^b)<<6 + (kc>>1)<<7
  const int B0  = (qq ^ (swz & 3)) << 4;
  const int b64 = (swz & 4) << 4;
  const int hE = l15 * 512 + B0 + b64;        // even kc, + (kc>>1)*128 imm
  const int hO = l15 * 512 + B0 + 64 - b64;   // odd  kc
  const int xE = l15 * 256 + B0 + b64;
  const int xO = l15 * 256 + B0 + 64 - b64;
  int woffH[2];
#pragma unroll
  for (int j = 0; j < 2; ++j)
    woffH[j] = l15 * 512 +
               (((wave * 4 + j * 2 + (qq >> 1)) ^ swz) << 4) + (qq & 1) * 8;

  __syncthreads();

  // x[t] B-frags, loop-carried (x[0] read from slot 0; thereafter read at
  // each step's phase 4 from the ring -- r5's read position)
  bf16x8 xb[4];
  xb[0] = *(const bf16x8*)(&lds[XOFF] + xE);
  xb[1] = *(const bf16x8*)(&lds[XOFF] + xO);
  xb[2] = *(const bf16x8*)(&lds[XOFF] + xE + 128);
  xb[3] = *(const bf16x8*)(&lds[XOFF] + xO + 128);

  // ---- one RNN step (ph = t&3, compile-time at every callsite) ----
  auto stepf = [&](int t, const int ph) {
    const char* hR = &lds[(ph & 1) * HREG];          // h[t]
    char*       hW = &lds[((ph & 1) ^ 1) * HREG];    // h[t+1]
    const char* xR = &lds[XOFF + ((ph + 1) & 3) * XSLOT];  // x[t+1]
    char*       xW = &lds[XOFF + ((ph + 2) & 3) * XSLOT];  // x[t+2]

    // 1) h B-frag reads (head of the post-barrier chain)
    bf16x8 hbA[4], hbB[4];
    hbA[0] = *(const bf16x8*)(hR + hE);
    hbA[1] = *(const bf16x8*)(hR + hO);
    hbA[2] = *(const bf16x8*)(hR + hE + 128);
    hbA[3] = *(const bf16x8*)(hR + hO + 128);
    hbB[0] = *(const bf16x8*)(hR + hE + 256);
    hbB[1] = *(const bf16x8*)(hR + hO + 256);
    hbB[2] = *(const bf16x8*)(hR + hE + 384);
    hbB[3] = *(const bf16x8*)(hR + hO + 384);

    // 2) x[t+3] HBM prefetch (full step of latency cover)
    loadx(t + 3, (ph + 1) & 1);

    // 3) MFMA cluster. Exact r5 chain order per accumulator (x kc0-3 then
    //    h kc0-7): bitwise-identical trajectory to r5. The x-MFMAs consume
    //    registers only -> they execute while the h-reads return.
    __builtin_amdgcn_s_setprio(1);
    const fx4 z4 = {0.f, 0.f, 0.f, 0.f};
    fx4 accL = z4, acc0 = z4, acc1 = z4;
#pragma unroll
    for (int kc = 0; kc < 4; ++kc) {
      accL = __builtin_amdgcn_mfma_f32_16x16x32_bf16(Wfr[2][kc], xb[kc], accL, 0, 0, 0);
      acc0 = __builtin_amdgcn_mfma_f32_16x16x32_bf16(Wfr[0][kc], xb[kc], acc0, 0, 0, 0);
      acc1 = __builtin_amdgcn_mfma_f32_16x16x32_bf16(Wfr[1][kc], xb[kc], acc1, 0, 0, 0);
    }
#pragma unroll
    for (int kc = 0; kc < 4; ++kc) {
      accL = __builtin_amdgcn_mfma_f32_16x16x32_bf16(Wfr[2][kc + 4], hbA[kc], accL, 0, 0, 0);
      acc0 = __builtin_amdgcn_mfma_f32_16x16x32_bf16(Wfr[0][kc + 4], hbA[kc], acc0, 0, 0, 0);
      acc1 = __builtin_amdgcn_mfma_f32_16x16x32_bf16(Wfr[1][kc + 4], hbA[kc], acc1, 0, 0, 0);
    }
#pragma unroll
    for (int kc = 0; kc < 4; ++kc) {
      accL = __builtin_amdgcn_mfma_f32_16x16x32_bf16(Wfr[2][kc + 8], hbB[kc], accL, 0, 0, 0);
      acc0 = __builtin_amdgcn_mfma_f32_16x16x32_bf16(Wfr[0][kc + 8], hbB[kc], acc0, 0, 0, 0);
      acc1 = __builtin_amdgcn_mfma_f32_16x16x32_bf16(Wfr[1][kc + 8], hbB[kc], acc1, 0, 0, 0);
    }
    __builtin_amdgcn_s_setprio(0);

    // 4) read x[t+1] B-frags for next step (r5 position; LDS latency hides
    //    under logits/epilogue; values live across the barrier in regs)
    if (ph != 3 || t + 1 < TT) {
      xb[0] = *(const bf16x8*)(xR + xE);
      xb[1] = *(const bf16x8*)(xR + xO);
      xb[2] = *(const bf16x8*)(xR + xE + 128);
      xb[3] = *(const bf16x8*)(xR + xO + 128);
    }

    // 5) logits: every lane has all 4 logits of its batch row
    const fx4 lg = accL + bo;
    int qi = 0; float bv = lg[0];
    if (lg[1] > bv) { bv = lg[1]; qi = 1; }
    if (lg[2] > bv) { bv = lg[2]; qi = 2; }
    if (lg[3] > bv) { bv = lg[3]; qi = 3; }
    if (wave == 0 && qq == 0)
      *(fx4*)&outs[((long)t * BBAT + b0 + l15) * 4] = lg;   // 256B coalesced

    // 6) gate select from packed-bf16 table (cndmask, no LDS)
    const bool s0 = (qi & 1) != 0, s1 = (qi & 2) != 0;
    const ui4 ga = s0 ? abf[1] : abf[0];
    const ui4 gb = s0 ? abf[3] : abf[2];
    const ui4 g  = s1 ? gb : ga;

    // 7) epilogue: th = tanh(acc+bias) = 1 - 2/(exp2(C2*acc + C2*b) + 1)
    const fx4 accj[2] = { acc0, acc1 };
#pragma unroll
    for (int j = 0; j < 2; ++j) {
      const fx4 z = accj[j] * C2 + cbz[j];
      fx4 th;
#pragma unroll
      for (int r = 0; r < 4; ++r) {
        const float e  = __builtin_amdgcn_exp2f(z[r]);
        const float rc = __builtin_amdgcn_rcpf(e + 1.0f);
        th[r] = fmaf(-2.0f, rc, 1.0f);
      }
      if (ph == 0 && t == 0)
        *(fx4*)&hs0[(long)(b0 + l15) * HDIM + (wave * 2 + j) * 16 + qq * 4] = th;
      // h_next = th + th*a  (a = act[qi][...] in bf16; |err| ~4e-5 << bf16-h ulp)
      const unsigned ug0 = g[j * 2 + 0], ug1 = g[j * 2 + 1];
      const float a0 = __builtin_bit_cast(float, ug0 << 16);
      const float a1 = __builtin_bit_cast(float, ug0 & 0xFFFF0000u);
      const float a2 = __builtin_bit_cast(float, ug1 << 16);
      const float a3 = __builtin_bit_cast(float, ug1 & 0xFFFF0000u);
      fx4 hg;
      hg[0] = fmaf(th[0], a0, th[0]);
      hg[1] = fmaf(th[1], a1, th[1]);
      hg[2] = fmaf(th[2], a2, th[2]);
      hg[3] = fmaf(th[3], a3, th[3]);
      union { unsigned long long u; __hip_bfloat162 h2[2]; } pk;
      pk.h2[0] = __float22bfloat162_rn(make_float2(hg[0], hg[1]));
      pk.h2[1] = __float22bfloat162_rn(make_float2(hg[2], hg[3]));
      *(unsigned long long*)(hW + woffH[j]) = pk.u;
    }

    // 8) stage x[t+2] (loaded at step t-1) into ring slot (t+2)&3
    if (ph < 2 || t + 2 < TT) writex(ph & 1, xW);

    ldsbar();   // single barrier per step
  };

#pragma unroll 1
  for (int t = 0; t < TT; t += 4) {
    stepf(t,     0);
    stepf(t + 1, 1);
    stepf(t + 2, 2);
    stepf(t + 3, 3);
  }
}

extern "C" void kernel_launch(void* const* d_in, const int* in_sizes, int n_in,
                              void* d_out, int out_size, void* d_ws, size_t ws_size,
                              hipStream_t stream) {
  const float* inp    = (const float*)d_in[0];
  const float* hidden = (const float*)d_in[1];
  const float* Wih    = (const float*)d_in[2];
  const float* bih    = (const float*)d_in[3];
  const float* Wio    = (const float*)d_in[4];
  const float* bio    = (const float*)d_in[5];
  const float* act    = (const float*)d_in[6];
  float* out = (float*)d_out;
  rnn_fused<<<dim3(BBAT / NB), dim3(512), 0, stream>>>(
      inp, hidden, Wih, bih, Wio, bio, act, out);
}

// Round 5
// 830.412 us; speedup vs baseline: 1.4207x; 1.0037x over previous
//
#include <hip/hip_runtime.h>
#include <hip/hip_bf16.h>

// SimpleRNN fused persistent kernel, round 9.
// T=512, B=1024, IN=128, H=256, OUT=4, K=384. 64 WGs x 16 batch rows, 8 waves.
// r8 post-mortem: r8 = r5 + {x-MFMAs moved post-barrier} + {setprio} regressed
// 532->581us with absmax bit-identical (0.03125) -- a pure scheduling loss.
// Suspect: setprio(1) in a barrier-lockstep structure (m190: null-to-negative
// on lockstep GEMM). Mechanism: post-barrier, the prio-1 MFMA wave starves its
// SIMD-partner's prio-0 ds_reads -> partner reaches the barrier late ->
// additive per-step penalty (counters: uniform slowdown, no contention
// counter moved).
// r9 = r8 MINUS setprio, exactly (one-line isolation; numerics untouched):
//   <=532 -> setprio was the bug, x-MFMA move vindicated.
//   ~580  -> x-MFMA move is the culprit; r10 reverts to r5 structure.

#define TT    512
#define BBAT  1024
#define INDIM 128
#define HDIM  256
#define KDIM  384
#define NB    16
#define HREG  8192    // one h buffer: 16 rows x 512 B (ping-pong at 0 / HREG)
#define XOFF  16384   // x ring: 4 slots x 4096 B (16 rows x 256 B)
#define XSLOT 4096

typedef __attribute__((ext_vector_type(8))) __bf16 bf16x8;
typedef __attribute__((ext_vector_type(4))) float  fx4;
typedef __attribute__((ext_vector_type(4))) unsigned int ui4;

__device__ __forceinline__ __bf16 f2bf(float f) {
  unsigned u = __builtin_bit_cast(unsigned, f);
  unsigned short r = (unsigned short)((u + 0x7FFFu + ((u >> 16) & 1u)) >> 16);
  return __builtin_bit_cast(__bf16, r);
}

// LDS-only barrier: waits DS ops, does NOT drain vmcnt (in-flight global
// loads/stores are wave-private; all cross-wave traffic goes through LDS).
__device__ __forceinline__ void ldsbar() {
  asm volatile("s_waitcnt lgkmcnt(0)\n\ts_barrier" ::: "memory");
}

__global__ __launch_bounds__(512, 2) void rnn_fused(
    const float* __restrict__ inp,     // [T,B,IN]
    const float* __restrict__ hidden,  // [B,H]
    const float* __restrict__ Wih,     // [H, K]
    const float* __restrict__ bih,     // [H]
    const float* __restrict__ Wio,     // [4, K]
    const float* __restrict__ bio,     // [4]
    const float* __restrict__ act,     // [4, H]
    float* __restrict__ out)           // [T*B*4] ++ [B*H]
{
  __shared__ __align__(16) char lds[2 * HREG + 4 * XSLOT];

  const int tid  = threadIdx.x;
  const int wave = tid >> 6;    // [0,8): h-tiles {2w, 2w+1}
  const int lane = tid & 63;
  const int l15  = lane & 15;   // batch row (B-frag col / D col)
  const int qq   = lane >> 4;
  const int b0   = blockIdx.x * NB;
  const int swz  = l15 & 7;

  float* outs = out;
  float* hs0  = out + (long)TT * BBAT * 4;

  const float C2 = 2.8853900817779268f;  // 2*log2(e)

  // ---- x pipeline: 512-thread cooperative staging, 2-reg ring ----
  const int xrow = tid >> 5, xcg = tid & 31;   // row[0,16) x 4-float chunk[0,32)
  fx4 xs[2];                                    // x[m] lives in xs[m&1]
  auto loadx = [&](int t, int s) {
    if (t < TT)
      xs[s] = *(const fx4*)(inp + ((long)t * BBAT + b0 + xrow) * INDIM + xcg * 4);
  };
  const int xwoff = xrow * 256 + (((xcg >> 1) ^ (xrow & 7)) << 4) + (xcg & 1) * 8;
  auto writex = [&](int s, char* dst) {
    union { unsigned long long u; __hip_bfloat162 h2[2]; } pk;
    pk.h2[0] = __float22bfloat162_rn(make_float2(xs[s][0], xs[s][1]));
    pk.h2[1] = __float22bfloat162_rn(make_float2(xs[s][2], xs[s][3]));
    *(unsigned long long*)(dst + xwoff) = pk.u;
  };

  // ---- one-time init: h0 -> hbuf0, x0/x1 -> ring slots 0/1, x2 -> xs[0] ----
  loadx(0, 0);
  {
    const int row = tid >> 5, cg = tid & 31;   // 8 floats of h per thread
    const float* hp = hidden + (long)(b0 + row) * HDIM + cg * 8;
    union { ui4 v; __hip_bfloat162 h2[4]; } pk;
    pk.h2[0] = __float22bfloat162_rn(make_float2(hp[0], hp[1]));
    pk.h2[1] = __float22bfloat162_rn(make_float2(hp[2], hp[3]));
    pk.h2[2] = __float22bfloat162_rn(make_float2(hp[4], hp[5]));
    pk.h2[3] = __float22bfloat162_rn(make_float2(hp[6], hp[7]));
    *(ui4*)(&lds[0] + row * 512 + ((cg ^ (row & 7)) << 4)) = pk.v;
  }
  writex(0, &lds[XOFF + 0 * XSLOT]);   // x[0] -> slot 0
  loadx(1, 1);
  writex(1, &lds[XOFF + 1 * XSLOT]);   // x[1] -> slot 1
  loadx(2, 0);                          // x[2] staged at step-0 tail

  // ---- loop-invariant weight A-frags: 2 h-tiles + replicated logits tile ----
  bf16x8 Wfr[3][12];
#pragma unroll
  for (int j = 0; j < 3; ++j) {
    const float* wbase = (j < 2) ? (Wih + (long)((wave * 2 + j) * 16 + l15) * KDIM)
                                 : (Wio + (long)(l15 & 3) * KDIM);
#pragma unroll
    for (int kc = 0; kc < 12; ++kc) {
      const float* wp = wbase + kc * 32 + qq * 8;
      bf16x8 f;
#pragma unroll
      for (int i = 0; i < 8; ++i) f[i] = f2bf(wp[i]);
      Wfr[j][kc] = f;
    }
  }

  // gates packed bf16: abf[qi] elems (j*4+r) = act[qi][(wave*2+j)*16+qq*4+r]
  ui4 abf[4];
#pragma unroll
  for (int qi = 0; qi < 4; ++qi) {
    const fx4 a0 = *(const fx4*)&act[qi * HDIM + (wave * 2 + 0) * 16 + qq * 4];
    const fx4 a1 = *(const fx4*)&act[qi * HDIM + (wave * 2 + 1) * 16 + qq * 4];
    union { ui4 v; __hip_bfloat162 h2[4]; } pk;
    pk.h2[0] = __float22bfloat162_rn(make_float2(a0[0], a0[1]));
    pk.h2[1] = __float22bfloat162_rn(make_float2(a0[2], a0[3]));
    pk.h2[2] = __float22bfloat162_rn(make_float2(a1[0], a1[1]));
    pk.h2[3] = __float22bfloat162_rn(make_float2(a1[2], a1[3]));
    abf[qi] = pk.v;
  }

  fx4 cbz[2];
#pragma unroll
  for (int j = 0; j < 2; ++j)
    cbz[j] = (*(const fx4*)&bih[(wave * 2 + j) * 16 + qq * 4]) * C2;
  const fx4 bo = *(const fx4*)&bio[0];

  // ---- collapsed swizzled LDS offsets ----
  // chunk(kc) = (kc*4+qq)^swz  ->  off = B0 + ((kc&1)^b)<<6 + (kc>>1)<<7
  const int B0  = (qq ^ (swz & 3)) << 4;
  const int b64 = (swz & 4) << 4;
  const int hE = l15 * 512 + B0 + b64;        // even kc, + (kc>>1)*128 imm
  const int hO = l15 * 512 + B0 + 64 - b64;   // odd  kc
  const int xE = l15 * 256 + B0 + b64;
  const int xO = l15 * 256 + B0 + 64 - b64;
  int woffH[2];
#pragma unroll
  for (int j = 0; j < 2; ++j)
    woffH[j] = l15 * 512 +
               (((wave * 4 + j * 2 + (qq >> 1)) ^ swz) << 4) + (qq & 1) * 8;

  __syncthreads();

  // x[t] B-frags, loop-carried (x[0] read from slot 0; thereafter read at
  // each step's phase 4 from the ring)
  bf16x8 xb[4];
  xb[0] = *(const bf16x8*)(&lds[XOFF] + xE);
  xb[1] = *(const bf16x8*)(&lds[XOFF] + xO);
  xb[2] = *(const bf16x8*)(&lds[XOFF] + xE + 128);
  xb[3] = *(const bf16x8*)(&lds[XOFF] + xO + 128);

  // ---- one RNN step (ph = t&3, compile-time at every callsite) ----
  auto stepf = [&](int t, const int ph) {
    const char* hR = &lds[(ph & 1) * HREG];          // h[t]
    char*       hW = &lds[((ph & 1) ^ 1) * HREG];    // h[t+1]
    const char* xR = &lds[XOFF + ((ph + 1) & 3) * XSLOT];  // x[t+1]
    char*       xW = &lds[XOFF + ((ph + 2) & 3) * XSLOT];  // x[t+2]

    // 1) h B-frag reads (head of the post-barrier chain)
    bf16x8 hbA[4], hbB[4];
    hbA[0] = *(const bf16x8*)(hR + hE);
    hbA[1] = *(const bf16x8*)(hR + hO);
    hbA[2] = *(const bf16x8*)(hR + hE + 128);
    hbA[3] = *(const bf16x8*)(hR + hO + 128);
    hbB[0] = *(const bf16x8*)(hR + hE + 256);
    hbB[1] = *(const bf16x8*)(hR + hO + 256);
    hbB[2] = *(const bf16x8*)(hR + hE + 384);
    hbB[3] = *(const bf16x8*)(hR + hO + 384);

    // 2) x[t+3] HBM prefetch (full step of latency cover)
    loadx(t + 3, (ph + 1) & 1);

    // 3) MFMA cluster. Exact r5 chain order per accumulator (x kc0-3 then
    //    h kc0-7): bitwise-identical trajectory to r5. The x-MFMAs consume
    //    registers only -> they execute while the h-reads return.
    const fx4 z4 = {0.f, 0.f, 0.f, 0.f};
    fx4 accL = z4, acc0 = z4, acc1 = z4;
#pragma unroll
    for (int kc = 0; kc < 4; ++kc) {
      accL = __builtin_amdgcn_mfma_f32_16x16x32_bf16(Wfr[2][kc], xb[kc], accL, 0, 0, 0);
      acc0 = __builtin_amdgcn_mfma_f32_16x16x32_bf16(Wfr[0][kc], xb[kc], acc0, 0, 0, 0);
      acc1 = __builtin_amdgcn_mfma_f32_16x16x32_bf16(Wfr[1][kc], xb[kc], acc1, 0, 0, 0);
    }
#pragma unroll
    for (int kc = 0; kc < 4; ++kc) {
      accL = __builtin_amdgcn_mfma_f32_16x16x32_bf16(Wfr[2][kc + 4], hbA[kc], accL, 0, 0, 0);
      acc0 = __builtin_amdgcn_mfma_f32_16x16x32_bf16(Wfr[0][kc + 4], hbA[kc], acc0, 0, 0, 0);
      acc1 = __builtin_amdgcn_mfma_f32_16x16x32_bf16(Wfr[1][kc + 4], hbA[kc], acc1, 0, 0, 0);
    }
#pragma unroll
    for (int kc = 0; kc < 4; ++kc) {
      accL = __builtin_amdgcn_mfma_f32_16x16x32_bf16(Wfr[2][kc + 8], hbB[kc], accL, 0, 0, 0);
      acc0 = __builtin_amdgcn_mfma_f32_16x16x32_bf16(Wfr[0][kc + 8], hbB[kc], acc0, 0, 0, 0);
      acc1 = __builtin_amdgcn_mfma_f32_16x16x32_bf16(Wfr[1][kc + 8], hbB[kc], acc1, 0, 0, 0);
    }

    // 4) read x[t+1] B-frags for next step (LDS latency hides under
    //    logits/epilogue; values live across the barrier in regs)
    if (ph != 3 || t + 1 < TT) {
      xb[0] = *(const bf16x8*)(xR + xE);
      xb[1] = *(const bf16x8*)(xR + xO);
      xb[2] = *(const bf16x8*)(xR + xE + 128);
      xb[3] = *(const bf16x8*)(xR + xO + 128);
    }

    // 5) logits: every lane has all 4 logits of its batch row
    const fx4 lg = accL + bo;
    int qi = 0; float bv = lg[0];
    if (lg[1] > bv) { bv = lg[1]; qi = 1; }
    if (lg[2] > bv) { bv = lg[2]; qi = 2; }
    if (lg[3] > bv) { bv = lg[3]; qi = 3; }
    if (wave == 0 && qq == 0)
      *(fx4*)&outs[((long)t * BBAT + b0 + l15) * 4] = lg;   // 256B coalesced

    // 6) gate select from packed-bf16 table (cndmask, no LDS)
    const bool s0 = (qi & 1) != 0, s1 = (qi & 2) != 0;
    const ui4 ga = s0 ? abf[1] : abf[0];
    const ui4 gb = s0 ? abf[3] : abf[2];
    const ui4 g  = s1 ? gb : ga;

    // 7) epilogue: th = tanh(acc+bias) = 1 - 2/(exp2(C2*acc + C2*b) + 1)
    const fx4 accj[2] = { acc0, acc1 };
#pragma unroll
    for (int j = 0; j < 2; ++j) {
      const fx4 z = accj[j] * C2 + cbz[j];
      fx4 th;
#pragma unroll
      for (int r = 0; r < 4; ++r) {
        const float e  = __builtin_amdgcn_exp2f(z[r]);
        const float rc = __builtin_amdgcn_rcpf(e + 1.0f);
        th[r] = fmaf(-2.0f, rc, 1.0f);
      }
      if (ph == 0 && t == 0)
        *(fx4*)&hs0[(long)(b0 + l15) * HDIM + (wave * 2 + j) * 16 + qq * 4] = th;
      // h_next = th + th*a  (a = act[qi][...] in bf16; |err| ~4e-5 << bf16-h ulp)
      const unsigned ug0 = g[j * 2 + 0], ug1 = g[j * 2 + 1];
      const float a0 = __builtin_bit_cast(float, ug0 << 16);
      const float a1 = __builtin_bit_cast(float, ug0 & 0xFFFF0000u);
      const float a2 = __builtin_bit_cast(float, ug1 << 16);
      const float a3 = __builtin_bit_cast(float, ug1 & 0xFFFF0000u);
      fx4 hg;
      hg[0] = fmaf(th[0], a0, th[0]);
      hg[1] = fmaf(th[1], a1, th[1]);
      hg[2] = fmaf(th[2], a2, th[2]);
      hg[3] = fmaf(th[3], a3, th[3]);
      union { unsigned long long u; __hip_bfloat162 h2[2]; } pk;
      pk.h2[0] = __float22bfloat162_rn(make_float2(hg[0], hg[1]));
      pk.h2[1] = __float22bfloat162_rn(make_float2(hg[2], hg[3]));
      *(unsigned long long*)(hW + woffH[j]) = pk.u;
    }

    // 8) stage x[t+2] (loaded at step t-1) into ring slot (t+2)&3
    if (ph < 2 || t + 2 < TT) writex(ph & 1, xW);

    ldsbar();   // single barrier per step
  };

#pragma unroll 1
  for (int t = 0; t < TT; t += 4) {
    stepf(t,     0);
    stepf(t + 1, 1);
    stepf(t + 2, 2);
    stepf(t + 3, 3);
  }
}

extern "C" void kernel_launch(void* const* d_in, const int* in_sizes, int n_in,
                              void* d_out, int out_size, void* d_ws, size_t ws_size,
                              hipStream_t stream) {
  const float* inp    = (const float*)d_in[0];
  const float* hidden = (const float*)d_in[1];
  const float* Wih    = (const float*)d_in[2];
  const float* bih    = (const float*)d_in[3];
  const float* Wio    = (const float*)d_in[4];
  const float* bio    = (const float*)d_in[5];
  const float* act    = (const float*)d_in[6];
  float* out = (float*)d_out;
  rnn_fused<<<dim3(BBAT / NB), dim3(512), 0, stream>>>(
      inp, hidden, Wih, bih, Wio, bio, act, out);
}

// Round 6
// 780.243 us; speedup vs baseline: 1.5120x; 1.0643x over previous
//
#include <hip/hip_runtime.h>
#include <hip/hip_bf16.h>

// SimpleRNN fused persistent kernel, round 10.
// T=512, B=1024, IN=128, H=256, OUT=4, K=384. 64 WGs x 16 batch rows, 8 waves.
// r9 post-mortem: setprio was null; the x-MFMA move to the cluster head cost
// the 48us (post-barrier dependent path to accL grew 24->36 MFMAs; the
// logits->argmax->gate->tanh->h-write chain that gates barrier arrival
// started ~12 MFMA slots later). r10 REVERTS to r5's exact dataflow
// (x-MFMAs at the step tail, acc loop-carried across the barrier, no
// setprio) and adds ONE bitwise-safe delta:
//  - intra-cluster reorder of the 24 h-MFMAs: accL (argmax-critical)
//    finishes at slot 17 (was 22), acc0 (first epilogue consumer) at 20
//    (was 23); acc1's last 4 MFMAs run at the end, overlapping the
//    argmax/gate/epilogue-j0 VALU+trans work on different pipes.
//    Per-accumulator kc order unchanged -> bitwise-identical trajectory.

#define TT    512
#define BBAT  1024
#define INDIM 128
#define HDIM  256
#define KDIM  384
#define NB    16
#define HREG  8192    // one h buffer: 16 rows x 512 B (ping-pong at 0 / HREG)
#define XOFF  16384   // x ring: 4 slots x 4096 B (16 rows x 256 B)
#define XSLOT 4096

typedef __attribute__((ext_vector_type(8))) __bf16 bf16x8;
typedef __attribute__((ext_vector_type(4))) float  fx4;
typedef __attribute__((ext_vector_type(4))) unsigned int ui4;

__device__ __forceinline__ __bf16 f2bf(float f) {
  unsigned u = __builtin_bit_cast(unsigned, f);
  unsigned short r = (unsigned short)((u + 0x7FFFu + ((u >> 16) & 1u)) >> 16);
  return __builtin_bit_cast(__bf16, r);
}

// LDS-only barrier: waits DS ops, does NOT drain vmcnt (in-flight global
// loads/stores are wave-private; all cross-wave traffic goes through LDS).
__device__ __forceinline__ void ldsbar() {
  asm volatile("s_waitcnt lgkmcnt(0)\n\ts_barrier" ::: "memory");
}

__global__ __launch_bounds__(512, 2) void rnn_fused(
    const float* __restrict__ inp,     // [T,B,IN]
    const float* __restrict__ hidden,  // [B,H]
    const float* __restrict__ Wih,     // [H, K]
    const float* __restrict__ bih,     // [H]
    const float* __restrict__ Wio,     // [4, K]
    const float* __restrict__ bio,     // [4]
    const float* __restrict__ act,     // [4, H]
    float* __restrict__ out)           // [T*B*4] ++ [B*H]
{
  __shared__ __align__(16) char lds[2 * HREG + 4 * XSLOT];

  const int tid  = threadIdx.x;
  const int wave = tid >> 6;    // [0,8): h-tiles {2w, 2w+1}
  const int lane = tid & 63;
  const int l15  = lane & 15;   // batch row (B-frag col / D col)
  const int qq   = lane >> 4;
  const int b0   = blockIdx.x * NB;
  const int swz  = l15 & 7;

  float* outs = out;
  float* hs0  = out + (long)TT * BBAT * 4;

  const float C2 = 2.8853900817779268f;  // 2*log2(e)

  // ---- x pipeline: 512-thread cooperative staging, 2-reg ring ----
  const int xrow = tid >> 5, xcg = tid & 31;   // row[0,16) x 4-float chunk[0,32)
  fx4 xs[2];                                    // x[m] lives in xs[m&1]
  auto loadx = [&](int t, int s) {
    if (t < TT)
      xs[s] = *(const fx4*)(inp + ((long)t * BBAT + b0 + xrow) * INDIM + xcg * 4);
  };
  const int xwoff = xrow * 256 + (((xcg >> 1) ^ (xrow & 7)) << 4) + (xcg & 1) * 8;
  auto writex = [&](int s, char* dst) {
    union { unsigned long long u; __hip_bfloat162 h2[2]; } pk;
    pk.h2[0] = __float22bfloat162_rn(make_float2(xs[s][0], xs[s][1]));
    pk.h2[1] = __float22bfloat162_rn(make_float2(xs[s][2], xs[s][3]));
    *(unsigned long long*)(dst + xwoff) = pk.u;
  };

  // ---- one-time init: h0 -> hbuf0, x0/x1 -> ring slots 0/1, x2 -> xs[0] ----
  loadx(0, 0);
  {
    const int row = tid >> 5, cg = tid & 31;   // 8 floats of h per thread
    const float* hp = hidden + (long)(b0 + row) * HDIM + cg * 8;
    union { ui4 v; __hip_bfloat162 h2[4]; } pk;
    pk.h2[0] = __float22bfloat162_rn(make_float2(hp[0], hp[1]));
    pk.h2[1] = __float22bfloat162_rn(make_float2(hp[2], hp[3]));
    pk.h2[2] = __float22bfloat162_rn(make_float2(hp[4], hp[5]));
    pk.h2[3] = __float22bfloat162_rn(make_float2(hp[6], hp[7]));
    *(ui4*)(&lds[0] + row * 512 + ((cg ^ (row & 7)) << 4)) = pk.v;
  }
  writex(0, &lds[XOFF + 0 * XSLOT]);   // x[0] -> slot 0
  loadx(1, 1);
  writex(1, &lds[XOFF + 1 * XSLOT]);   // x[1] -> slot 1
  loadx(2, 0);                          // x[2] staged at step-0 tail

  // ---- loop-invariant weight A-frags: 2 h-tiles + replicated logits tile ----
  bf16x8 Wfr[3][12];
#pragma unroll
  for (int j = 0; j < 3; ++j) {
    const float* wbase = (j < 2) ? (Wih + (long)((wave * 2 + j) * 16 + l15) * KDIM)
                                 : (Wio + (long)(l15 & 3) * KDIM);
#pragma unroll
    for (int kc = 0; kc < 12; ++kc) {
      const float* wp = wbase + kc * 32 + qq * 8;
      bf16x8 f;
#pragma unroll
      for (int i = 0; i < 8; ++i) f[i] = f2bf(wp[i]);
      Wfr[j][kc] = f;
    }
  }

  // gates packed bf16: abf[qi] elems (j*4+r) = act[qi][(wave*2+j)*16+qq*4+r]
  ui4 abf[4];
#pragma unroll
  for (int qi = 0; qi < 4; ++qi) {
    const fx4 a0 = *(const fx4*)&act[qi * HDIM + (wave * 2 + 0) * 16 + qq * 4];
    const fx4 a1 = *(const fx4*)&act[qi * HDIM + (wave * 2 + 1) * 16 + qq * 4];
    union { ui4 v; __hip_bfloat162 h2[4]; } pk;
    pk.h2[0] = __float22bfloat162_rn(make_float2(a0[0], a0[1]));
    pk.h2[1] = __float22bfloat162_rn(make_float2(a0[2], a0[3]));
    pk.h2[2] = __float22bfloat162_rn(make_float2(a1[0], a1[1]));
    pk.h2[3] = __float22bfloat162_rn(make_float2(a1[2], a1[3]));
    abf[qi] = pk.v;
  }

  fx4 cbz[2];
#pragma unroll
  for (int j = 0; j < 2; ++j)
    cbz[j] = (*(const fx4*)&bih[(wave * 2 + j) * 16 + qq * 4]) * C2;
  const fx4 bo = *(const fx4*)&bio[0];

  // ---- collapsed swizzled LDS offsets ----
  // chunk(kc) = (kc*4+qq)^swz  ->  off = B0 + ((kc&1)^b)<<6 + (kc>>1)<<7
  const int B0  = (qq ^ (swz & 3)) << 4;
  const int b64 = (swz & 4) << 4;
  const int hE = l15 * 512 + B0 + b64;        // even kc, + (kc>>1)*128 imm
  const int hO = l15 * 512 + B0 + 64 - b64;   // odd  kc
  const int xE = l15 * 256 + B0 + b64;
  const int xO = l15 * 256 + B0 + 64 - b64;
  int woffH[2];
#pragma unroll
  for (int j = 0; j < 2; ++j)
    woffH[j] = l15 * 512 +
               (((wave * 4 + j * 2 + (qq >> 1)) ^ swz) << 4) + (qq & 1) * 8;

  __syncthreads();

  // accumulators persist across steps: at loop top they hold x[t]-part
  fx4 acc[2], accL;
  {
    const char* xR = &lds[XOFF];   // x[0] in slot 0
    bf16x8 xb[4];
    xb[0] = *(const bf16x8*)(xR + xE);
    xb[1] = *(const bf16x8*)(xR + xO);
    xb[2] = *(const bf16x8*)(xR + xE + 128);
    xb[3] = *(const bf16x8*)(xR + xO + 128);
    const fx4 z4 = {0.f, 0.f, 0.f, 0.f};
    accL = z4; acc[0] = z4; acc[1] = z4;
#pragma unroll
    for (int kc = 0; kc < 4; ++kc) {
      accL   = __builtin_amdgcn_mfma_f32_16x16x32_bf16(Wfr[2][kc], xb[kc], accL, 0, 0, 0);
      acc[0] = __builtin_amdgcn_mfma_f32_16x16x32_bf16(Wfr[0][kc], xb[kc], acc[0], 0, 0, 0);
      acc[1] = __builtin_amdgcn_mfma_f32_16x16x32_bf16(Wfr[1][kc], xb[kc], acc[1], 0, 0, 0);
    }
  }

  // ---- one RNN step (ph = t&3, compile-time at every callsite) ----
  auto stepf = [&](int t, const int ph) {
    const char* hR = &lds[(ph & 1) * HREG];          // h[t]
    char*       hW = &lds[((ph & 1) ^ 1) * HREG];    // h[t+1]
    const char* xR = &lds[XOFF + ((ph + 1) & 3) * XSLOT];  // x[t+1]
    char*       xW = &lds[XOFF + ((ph + 2) & 3) * XSLOT];  // x[t+2]

    // 1) h B-frag reads (head of the post-barrier chain), x HBM prefetch
    bf16x8 hbA[4], hbB[4];
    hbA[0] = *(const bf16x8*)(hR + hE);
    hbA[1] = *(const bf16x8*)(hR + hO);
    hbA[2] = *(const bf16x8*)(hR + hE + 128);
    hbA[3] = *(const bf16x8*)(hR + hO + 128);
    loadx(t + 3, (ph + 1) & 1);
    hbB[0] = *(const bf16x8*)(hR + hE + 256);
    hbB[1] = *(const bf16x8*)(hR + hO + 256);
    hbB[2] = *(const bf16x8*)(hR + hE + 384);
    hbB[3] = *(const bf16x8*)(hR + hO + 384);

    // 2) 24 h-MFMAs, accL-priority schedule: accL done at slot 17 (was 22),
    //    acc0 at 20 (was 23); acc1's last 4 at the end overlap the argmax/
    //    gate/epilogue VALU+trans work. Per-acc kc order unchanged (kc 4..11
    //    ascending) -> bitwise-identical to r5.
    accL   = __builtin_amdgcn_mfma_f32_16x16x32_bf16(Wfr[2][4], hbA[0], accL,   0, 0, 0);
    acc[0] = __builtin_amdgcn_mfma_f32_16x16x32_bf16(Wfr[0][4], hbA[0], acc[0], 0, 0, 0);
    acc[1] = __builtin_amdgcn_mfma_f32_16x16x32_bf16(Wfr[1][4], hbA[0], acc[1], 0, 0, 0);
    accL   = __builtin_amdgcn_mfma_f32_16x16x32_bf16(Wfr[2][5], hbA[1], accL,   0, 0, 0);
    acc[0] = __builtin_amdgcn_mfma_f32_16x16x32_bf16(Wfr[0][5], hbA[1], acc[0], 0, 0, 0);
    acc[1] = __builtin_amdgcn_mfma_f32_16x16x32_bf16(Wfr[1][5], hbA[1], acc[1], 0, 0, 0);
    accL   = __builtin_amdgcn_mfma_f32_16x16x32_bf16(Wfr[2][6], hbA[2], accL,   0, 0, 0);
    acc[0] = __builtin_amdgcn_mfma_f32_16x16x32_bf16(Wfr[0][6], hbA[2], acc[0], 0, 0, 0);
    accL   = __builtin_amdgcn_mfma_f32_16x16x32_bf16(Wfr[2][7], hbA[3], accL,   0, 0, 0);
    acc[0] = __builtin_amdgcn_mfma_f32_16x16x32_bf16(Wfr[0][7], hbA[3], acc[0], 0, 0, 0);
    accL   = __builtin_amdgcn_mfma_f32_16x16x32_bf16(Wfr[2][8], hbB[0], accL,   0, 0, 0);
    acc[0] = __builtin_amdgcn_mfma_f32_16x16x32_bf16(Wfr[0][8], hbB[0], acc[0], 0, 0, 0);
    accL   = __builtin_amdgcn_mfma_f32_16x16x32_bf16(Wfr[2][9], hbB[1], accL,   0, 0, 0);
    acc[0] = __builtin_amdgcn_mfma_f32_16x16x32_bf16(Wfr[0][9], hbB[1], acc[0], 0, 0, 0);
    accL   = __builtin_amdgcn_mfma_f32_16x16x32_bf16(Wfr[2][10], hbB[2], accL,   0, 0, 0);
    acc[0] = __builtin_amdgcn_mfma_f32_16x16x32_bf16(Wfr[0][10], hbB[2], acc[0], 0, 0, 0);
    accL   = __builtin_amdgcn_mfma_f32_16x16x32_bf16(Wfr[2][11], hbB[3], accL,   0, 0, 0);
    acc[1] = __builtin_amdgcn_mfma_f32_16x16x32_bf16(Wfr[1][6], hbA[2], acc[1], 0, 0, 0);
    acc[1] = __builtin_amdgcn_mfma_f32_16x16x32_bf16(Wfr[1][7], hbA[3], acc[1], 0, 0, 0);
    acc[0] = __builtin_amdgcn_mfma_f32_16x16x32_bf16(Wfr[0][11], hbB[3], acc[0], 0, 0, 0);
    acc[1] = __builtin_amdgcn_mfma_f32_16x16x32_bf16(Wfr[1][8], hbB[0], acc[1], 0, 0, 0);
    acc[1] = __builtin_amdgcn_mfma_f32_16x16x32_bf16(Wfr[1][9], hbB[1], acc[1], 0, 0, 0);
    acc[1] = __builtin_amdgcn_mfma_f32_16x16x32_bf16(Wfr[1][10], hbB[2], acc[1], 0, 0, 0);
    acc[1] = __builtin_amdgcn_mfma_f32_16x16x32_bf16(Wfr[1][11], hbB[3], acc[1], 0, 0, 0);

    // 3) read x[t+1] B-frags for next step (LDS latency hides under
    //    logits/epilogue)
    bf16x8 xb[4];
    if (ph != 3 || t + 1 < TT) {
      xb[0] = *(const bf16x8*)(xR + xE);
      xb[1] = *(const bf16x8*)(xR + xO);
      xb[2] = *(const bf16x8*)(xR + xE + 128);
      xb[3] = *(const bf16x8*)(xR + xO + 128);
    }

    // 4) logits: every lane has all 4 logits of its batch row
    const fx4 lg = accL + bo;
    int qi = 0; float bv = lg[0];
    if (lg[1] > bv) { bv = lg[1]; qi = 1; }
    if (lg[2] > bv) { bv = lg[2]; qi = 2; }
    if (lg[3] > bv) { bv = lg[3]; qi = 3; }
    if (wave == 0 && qq == 0)
      *(fx4*)&outs[((long)t * BBAT + b0 + l15) * 4] = lg;   // 256B coalesced

    // 5) gate select from packed-bf16 table (cndmask, no LDS)
    const bool s0 = (qi & 1) != 0, s1 = (qi & 2) != 0;
    const ui4 ga = s0 ? abf[1] : abf[0];
    const ui4 gb = s0 ? abf[3] : abf[2];
    const ui4 g  = s1 ? gb : ga;

    // 6) epilogue: th = tanh(acc+bias) = 1 - 2/(exp2(C2*acc + C2*b) + 1)
#pragma unroll
    for (int j = 0; j < 2; ++j) {
      const fx4 z = acc[j] * C2 + cbz[j];
      fx4 th;
#pragma unroll
      for (int r = 0; r < 4; ++r) {
        const float e  = __builtin_amdgcn_exp2f(z[r]);
        const float rc = __builtin_amdgcn_rcpf(e + 1.0f);
        th[r] = fmaf(-2.0f, rc, 1.0f);
      }
      if (ph == 0 && t == 0)
        *(fx4*)&hs0[(long)(b0 + l15) * HDIM + (wave * 2 + j) * 16 + qq * 4] = th;
      // h_next = th + th*a  (a = act[qi][...] in bf16; |err| ~4e-5 << bf16-h ulp)
      const unsigned ug0 = g[j * 2 + 0], ug1 = g[j * 2 + 1];
      const float a0 = __builtin_bit_cast(float, ug0 << 16);
      const float a1 = __builtin_bit_cast(float, ug0 & 0xFFFF0000u);
      const float a2 = __builtin_bit_cast(float, ug1 << 16);
      const float a3 = __builtin_bit_cast(float, ug1 & 0xFFFF0000u);
      fx4 hg;
      hg[0] = fmaf(th[0], a0, th[0]);
      hg[1] = fmaf(th[1], a1, th[1]);
      hg[2] = fmaf(th[2], a2, th[2]);
      hg[3] = fmaf(th[3], a3, th[3]);
      union { unsigned long long u; __hip_bfloat162 h2[2]; } pk;
      pk.h2[0] = __float22bfloat162_rn(make_float2(hg[0], hg[1]));
      pk.h2[1] = __float22bfloat162_rn(make_float2(hg[2], hg[3]));
      *(unsigned long long*)(hW + woffH[j]) = pk.u;
    }

    // 7) x-part MFMAs for step t+1 (step tail, after the h-write: off the
    //    inter-step critical path -- r5's verified position)
    if (ph != 3 || t + 1 < TT) {
      const fx4 z4 = {0.f, 0.f, 0.f, 0.f};
      accL = z4; acc[0] = z4; acc[1] = z4;
#pragma unroll
      for (int kc = 0; kc < 4; ++kc) {
        accL   = __builtin_amdgcn_mfma_f32_16x16x32_bf16(Wfr[2][kc], xb[kc], accL, 0, 0, 0);
        acc[0] = __builtin_amdgcn_mfma_f32_16x16x32_bf16(Wfr[0][kc], xb[kc], acc[0], 0, 0, 0);
        acc[1] = __builtin_amdgcn_mfma_f32_16x16x32_bf16(Wfr[1][kc], xb[kc], acc[1], 0, 0, 0);
      }
    }

    // 8) stage x[t+2] (loaded at step t-1) into ring slot (t+2)&3
    if (ph < 2 || t + 2 < TT) writex(ph & 1, xW);

    ldsbar();   // single barrier per step
  };

#pragma unroll 1
  for (int t = 0; t < TT; t += 4) {
    stepf(t,     0);
    stepf(t + 1, 1);
    stepf(t + 2, 2);
    stepf(t + 3, 3);
  }
}

extern "C" void kernel_launch(void* const* d_in, const int* in_sizes, int n_in,
                              void* d_out, int out_size, void* d_ws, size_t ws_size,
                              hipStream_t stream) {
  const float* inp    = (const float*)d_in[0];
  const float* hidden = (const float*)d_in[1];
  const float* Wih    = (const float*)d_in[2];
  const float* bih    = (const float*)d_in[3];
  const float* Wio    = (const float*)d_in[4];
  const float* bio    = (const float*)d_in[5];
  const float* act    = (const float*)d_in[6];
  float* out = (float*)d_out;
  rnn_fused<<<dim3(BBAT / NB), dim3(512), 0, stream>>>(
      inp, hidden, Wih, bih, Wio, bio, act, out);
}